// Round 1
// baseline (143.285 us; speedup 1.0000x reference)
//
#include <hip/hip_runtime.h>
#include <math.h>

#define EMBED   64
#define BATCH   2048
#define NTOT    (2*BATCH)        // 4096
#define NITEMS  10000
#define TILE    64
#define NT      (NTOT/TILE)      // 64
#define NTILES  (NT*(NT+1)/2)    // 2080
#define SSTR    66               // LDS row stride (floats): even -> 8B-aligned float2 reads,
                                 // write conflicts limited to 4-way

__device__ __forceinline__ int total_id(int x, const int* pos_id, const int* neg_id) {
    return (x < BATCH) ? pos_id[x] : neg_id[x - BATCH];
}

// One wave per row: gather item_table[total[row]] into ws and compute row norm.
__global__ __launch_bounds__(256) void prep_kernel(const int* __restrict__ pos_id,
                                                   const int* __restrict__ neg_id,
                                                   const float* __restrict__ item_table,
                                                   float* __restrict__ e_out,
                                                   float* __restrict__ sq_out) {
    int row  = (blockIdx.x * 256 + threadIdx.x) >> 6;
    int lane = threadIdx.x & 63;
    if (row >= NTOT) return;
    int id = total_id(row, pos_id, neg_id);
    float v = item_table[id * EMBED + lane];
    e_out[row * EMBED + lane] = v;
    float s = v * v;
    #pragma unroll
    for (int off = 32; off; off >>= 1) s += __shfl_xor(s, off, 64);
    if (lane == 0) sq_out[row] = s;
}

// One wave per batch element: pos/neg dots + stable softplus; per-block partial.
__global__ __launch_bounds__(256) void bpp_kernel(const int* __restrict__ user_id,
                                                  const int* __restrict__ pos_id,
                                                  const int* __restrict__ neg_id,
                                                  const float* __restrict__ user_table,
                                                  const float* __restrict__ item_table,
                                                  float* __restrict__ partials) {
    int idx  = blockIdx.x * 256 + threadIdx.x;
    int b    = idx >> 6;
    int lane = threadIdx.x & 63;
    float sp = 0.f;
    if (b < BATCH) {
        float u = user_table[user_id[b] * EMBED + lane];
        float p = item_table[pos_id[b]  * EMBED + lane];
        float n = item_table[neg_id[b]  * EMBED + lane];
        float dp = u * p, dn = u * n;
        #pragma unroll
        for (int off = 32; off; off >>= 1) {
            dp += __shfl_xor(dp, off, 64);
            dn += __shfl_xor(dn, off, 64);
        }
        float x = dn - dp;
        sp = fmaxf(x, 0.f) + log1pf(expf(-fabsf(x)));   // softplus, stable
    }
    __shared__ float red[4];
    if (lane == 0) red[threadIdx.x >> 6] = sp;
    __syncthreads();
    if (threadIdx.x == 0) partials[blockIdx.x] = red[0] + red[1] + red[2] + red[3];
}

// One block per upper-triangular 64x64 tile pair.
__global__ __launch_bounds__(256) void reg_kernel(const float* __restrict__ e,
                                                  const float* __restrict__ sq,
                                                  const int* __restrict__ pos_id,
                                                  const int* __restrict__ neg_id,
                                                  const float* __restrict__ D,
                                                  float* __restrict__ partials) {
    __shared__ float si[EMBED][SSTR];   // transposed: si[k][ii]
    __shared__ float sj[EMBED][SSTR];
    __shared__ float sqi[TILE], sqj[TILE];
    __shared__ int   idi[TILE], idj[TILE];

    int b = blockIdx.x;
    int tI = 0, rem = b;
    while (rem >= NT - tI) { rem -= NT - tI; ++tI; }
    int tJ = tI + rem;

    int t  = threadIdx.x;
    int kg = (t & 15) * 4;   // k-group base
    int r0 = t >> 4;         // row within 16-row chunk

    // Stage both tiles transposed. Global reads: float4, fully coalesced.
    #pragma unroll
    for (int it = 0; it < 4; ++it) {
        int r = r0 + it * 16;
        float4 vi = *(const float4*)&e[(tI * TILE + r) * EMBED + kg];
        float4 vj = *(const float4*)&e[(tJ * TILE + r) * EMBED + kg];
        si[kg + 0][r] = vi.x; si[kg + 1][r] = vi.y; si[kg + 2][r] = vi.z; si[kg + 3][r] = vi.w;
        sj[kg + 0][r] = vj.x; sj[kg + 1][r] = vj.y; sj[kg + 2][r] = vj.z; sj[kg + 3][r] = vj.w;
    }
    if (t < TILE) {
        sqi[t] = sq[tI * TILE + t];
        idi[t] = total_id(tI * TILE + t, pos_id, neg_id);
    } else if (t < 2 * TILE) {
        int r = t - TILE;
        sqj[r] = sq[tJ * TILE + r];
        idj[r] = total_id(tJ * TILE + r, pos_id, neg_id);
    }
    __syncthreads();

    // 4x4 register-blocked dot products.
    int ii0 = (t & 15) * 4;
    int jj0 = (t >> 4) * 4;
    float dot[4][4];
    #pragma unroll
    for (int a = 0; a < 4; ++a)
        #pragma unroll
        for (int c = 0; c < 4; ++c) dot[a][c] = 0.f;

    #pragma unroll 8
    for (int k = 0; k < EMBED; ++k) {
        float2 a01 = *(const float2*)&si[k][ii0];
        float2 a23 = *(const float2*)&si[k][ii0 + 2];
        float2 b01 = *(const float2*)&sj[k][jj0];
        float2 b23 = *(const float2*)&sj[k][jj0 + 2];
        float av[4] = {a01.x, a01.y, a23.x, a23.y};
        float bv[4] = {b01.x, b01.y, b23.x, b23.y};
        #pragma unroll
        for (int a = 0; a < 4; ++a)
            #pragma unroll
            for (int c = 0; c < 4; ++c)
                dot[a][c] = fmaf(av[a], bv[c], dot[a][c]);
    }

    // Masked distance * gathered D.
    float acc = 0.f;
    #pragma unroll
    for (int a = 0; a < 4; ++a) {
        int   i    = tI * TILE + ii0 + a;
        float sqa  = sqi[ii0 + a];
        int   roff = idi[ii0 + a] * NITEMS;   // < 1e8, fits int32
        #pragma unroll
        for (int c = 0; c < 4; ++c) {
            int j = tJ * TILE + jj0 + c;
            float d2 = sqa + sqj[jj0 + c] - 2.f * dot[a][c];
            if (i < j && d2 > 0.f) {
                acc += D[roff + idj[jj0 + c]] * sqrtf(d2);
            }
        }
    }

    __shared__ float red[256];
    red[t] = acc;
    __syncthreads();
    #pragma unroll
    for (int s = 128; s; s >>= 1) {
        if (t < s) red[t] += red[t + s];
        __syncthreads();
    }
    if (t == 0) partials[b] = red[0];
}

// Deterministic fixed-order final reduction; fully overwrites d_out.
__global__ __launch_bounds__(256) void reduce_kernel(const float* __restrict__ bpp_part,
                                                     const float* __restrict__ reg_part,
                                                     float* __restrict__ out) {
    int t = threadIdx.x;
    float s1 = 0.f, s2 = 0.f;
    for (int i = t; i < 512;    i += 256) s1 += bpp_part[i];
    for (int i = t; i < NTILES; i += 256) s2 += reg_part[i];
    __shared__ float r1[256], r2[256];
    r1[t] = s1; r2[t] = s2;
    __syncthreads();
    #pragma unroll
    for (int s = 128; s; s >>= 1) {
        if (t < s) { r1[t] += r1[t + s]; r2[t] += r2[t + s]; }
        __syncthreads();
    }
    if (t == 0) { out[0] = r1[0]; out[1] = r2[0]; }
}

extern "C" void kernel_launch(void* const* d_in, const int* in_sizes, int n_in,
                              void* d_out, int out_size, void* d_ws, size_t ws_size,
                              hipStream_t stream) {
    const int*   user_id    = (const int*)  d_in[0];
    const int*   pos_id     = (const int*)  d_in[1];
    const int*   neg_id     = (const int*)  d_in[2];
    const float* user_table = (const float*)d_in[3];
    const float* item_table = (const float*)d_in[4];
    const float* D          = (const float*)d_in[5];
    float* out = (float*)d_out;

    float* ws       = (float*)d_ws;
    float* e        = ws;                       // NTOT*EMBED
    float* sq       = e  + NTOT * EMBED;        // NTOT
    float* bpp_part = sq + NTOT;                // 512
    float* reg_part = bpp_part + 512;           // NTILES

    prep_kernel<<<NTOT / 4, 256, 0, stream>>>(pos_id, neg_id, item_table, e, sq);
    bpp_kernel<<<BATCH / 4, 256, 0, stream>>>(user_id, pos_id, neg_id, user_table, item_table, bpp_part);
    reg_kernel<<<NTILES, 256, 0, stream>>>(e, sq, pos_id, neg_id, D, reg_part);
    reduce_kernel<<<1, 256, 0, stream>>>(bpp_part, reg_part, out);
}

// Round 2
// 104.332 us; speedup vs baseline: 1.3734x; 1.3734x over previous
//
#include <hip/hip_runtime.h>
#include <math.h>

#define EMBED   64
#define BATCH   2048
#define NTOT    (2*BATCH)        // 4096
#define NITEMS  10000
#define TILE    64
#define NT      (NTOT/TILE)      // 64
#define NTILES  (NT*(NT+1)/2)    // 2080
#define SSTR    66               // LDS row stride (floats)

// Deterministic in-LDS bitonic sort of 4096 keys (id<<12 | orig_pos).
// Sorting by id clusters the D-gather addresses; orig_pos kept for
// orientation (D is not symmetric) and uniqueness (keys all distinct).
__global__ __launch_bounds__(1024) void sort_kernel(const int* __restrict__ pos_id,
                                                    const int* __restrict__ neg_id,
                                                    int* __restrict__ sorted_id,
                                                    int* __restrict__ sorted_orig) {
    __shared__ unsigned int key[NTOT];
    int t = threadIdx.x;
    for (int i = t; i < NTOT; i += 1024) {
        int id = (i < BATCH) ? pos_id[i] : neg_id[i - BATCH];
        key[i] = ((unsigned)id << 12) | (unsigned)i;
    }
    __syncthreads();
    for (int k = 2; k <= NTOT; k <<= 1) {
        for (int j = k >> 1; j > 0; j >>= 1) {
            #pragma unroll
            for (int rep = 0; rep < NTOT / 1024; ++rep) {
                int i = t + rep * 1024;
                int l = i ^ j;
                if (l > i) {
                    unsigned a = key[i], b = key[l];
                    bool up = (i & k) == 0;
                    if ((a > b) == up) { key[i] = b; key[l] = a; }
                }
            }
            __syncthreads();
        }
    }
    for (int i = t; i < NTOT; i += 1024) {
        sorted_id[i]   = (int)(key[i] >> 12);
        sorted_orig[i] = (int)(key[i] & 4095u);
    }
}

// One wave per sorted row: gather item_table[sorted_id[row]], compute norm.
__global__ __launch_bounds__(256) void prep_kernel(const int* __restrict__ sorted_id,
                                                   const float* __restrict__ item_table,
                                                   float* __restrict__ e_out,
                                                   float* __restrict__ sq_out) {
    int row  = (blockIdx.x * 256 + threadIdx.x) >> 6;
    int lane = threadIdx.x & 63;
    if (row >= NTOT) return;
    int id = sorted_id[row];
    float v = item_table[id * EMBED + lane];
    e_out[row * EMBED + lane] = v;
    float s = v * v;
    #pragma unroll
    for (int off = 32; off; off >>= 1) s += __shfl_xor(s, off, 64);
    if (lane == 0) sq_out[row] = s;
}

// One wave per batch element: pos/neg dots + stable softplus.
__global__ __launch_bounds__(256) void bpp_kernel(const int* __restrict__ user_id,
                                                  const int* __restrict__ pos_id,
                                                  const int* __restrict__ neg_id,
                                                  const float* __restrict__ user_table,
                                                  const float* __restrict__ item_table,
                                                  float* __restrict__ partials) {
    int idx  = blockIdx.x * 256 + threadIdx.x;
    int b    = idx >> 6;
    int lane = threadIdx.x & 63;
    float sp = 0.f;
    if (b < BATCH) {
        float u = user_table[user_id[b] * EMBED + lane];
        float p = item_table[pos_id[b]  * EMBED + lane];
        float n = item_table[neg_id[b]  * EMBED + lane];
        float dp = u * p, dn = u * n;
        #pragma unroll
        for (int off = 32; off; off >>= 1) {
            dp += __shfl_xor(dp, off, 64);
            dn += __shfl_xor(dn, off, 64);
        }
        float x = dn - dp;
        sp = fmaxf(x, 0.f) + log1pf(expf(-fabsf(x)));
    }
    __shared__ float red[4];
    if (lane == 0) red[threadIdx.x >> 6] = sp;
    __syncthreads();
    if (threadIdx.x == 0) partials[blockIdx.x] = red[0] + red[1] + red[2] + red[3];
}

// One block per upper-triangular 64x64 tile pair (sorted index space).
__global__ __launch_bounds__(256) void reg_kernel(const float* __restrict__ e,
                                                  const float* __restrict__ sq,
                                                  const int* __restrict__ sorted_id,
                                                  const int* __restrict__ sorted_orig,
                                                  const float* __restrict__ D,
                                                  float* __restrict__ partials) {
    __shared__ float si[EMBED][SSTR];   // transposed: si[k][ii]
    __shared__ float sj[EMBED][SSTR];
    __shared__ float sqi[TILE], sqj[TILE];
    __shared__ int   idi[TILE], idj[TILE];
    __shared__ int   idiN[TILE], idjN[TILE];   // id * NITEMS precomputed
    __shared__ int   ogi[TILE], ogj[TILE];

    int b = blockIdx.x;
    int tI = 0, rem = b;
    while (rem >= NT - tI) { rem -= NT - tI; ++tI; }
    int tJ = tI + rem;

    int t  = threadIdx.x;
    int kg = (t & 15) * 4;
    int r0 = t >> 4;

    #pragma unroll
    for (int it = 0; it < 4; ++it) {
        int r = r0 + it * 16;
        float4 vi = *(const float4*)&e[(tI * TILE + r) * EMBED + kg];
        float4 vj = *(const float4*)&e[(tJ * TILE + r) * EMBED + kg];
        si[kg + 0][r] = vi.x; si[kg + 1][r] = vi.y; si[kg + 2][r] = vi.z; si[kg + 3][r] = vi.w;
        sj[kg + 0][r] = vj.x; sj[kg + 1][r] = vj.y; sj[kg + 2][r] = vj.z; sj[kg + 3][r] = vj.w;
    }
    if (t < TILE) {
        int g = tI * TILE + t;
        sqi[t] = sq[g];
        int id = sorted_id[g];
        idi[t] = id; idiN[t] = id * NITEMS;
        ogi[t] = sorted_orig[g];
    } else if (t < 2 * TILE) {
        int r = t - TILE, g = tJ * TILE + r;
        sqj[r] = sq[g];
        int id = sorted_id[g];
        idj[r] = id; idjN[r] = id * NITEMS;
        ogj[r] = sorted_orig[g];
    }
    __syncthreads();

    int ii0 = (t & 15) * 4;
    int jj0 = (t >> 4) * 4;
    float dot[4][4];
    #pragma unroll
    for (int a = 0; a < 4; ++a)
        #pragma unroll
        for (int c = 0; c < 4; ++c) dot[a][c] = 0.f;

    #pragma unroll 8
    for (int k = 0; k < EMBED; ++k) {
        float2 a01 = *(const float2*)&si[k][ii0];
        float2 a23 = *(const float2*)&si[k][ii0 + 2];
        float2 b01 = *(const float2*)&sj[k][jj0];
        float2 b23 = *(const float2*)&sj[k][jj0 + 2];
        float av[4] = {a01.x, a01.y, a23.x, a23.y};
        float bv[4] = {b01.x, b01.y, b23.x, b23.y};
        #pragma unroll
        for (int a = 0; a < 4; ++a)
            #pragma unroll
            for (int c = 0; c < 4; ++c)
                dot[a][c] = fmaf(av[a], bv[c], dot[a][c]);
    }

    float acc = 0.f;
    #pragma unroll
    for (int a = 0; a < 4; ++a) {
        int   i   = tI * TILE + ii0 + a;
        float sqa = sqi[ii0 + a];
        int   ida = idi[ii0 + a], idaN = idiN[ii0 + a], oa = ogi[ii0 + a];
        #pragma unroll
        for (int c = 0; c < 4; ++c) {
            int j = tJ * TILE + jj0 + c;
            float d2 = sqa + sqj[jj0 + c] - 2.f * dot[a][c];
            if (i < j && d2 > 0.f) {
                // orientation by ORIGINAL positions (D not symmetric)
                bool fwd = oa < ogj[jj0 + c];
                int addr = fwd ? (idaN + idj[jj0 + c]) : (idjN[jj0 + c] + ida);
                acc += D[addr] * sqrtf(d2);
            }
        }
    }

    __shared__ float red[256];
    red[t] = acc;
    __syncthreads();
    #pragma unroll
    for (int s = 128; s; s >>= 1) {
        if (t < s) red[t] += red[t + s];
        __syncthreads();
    }
    if (t == 0) partials[b] = red[0];
}

__global__ __launch_bounds__(256) void reduce_kernel(const float* __restrict__ bpp_part,
                                                     const float* __restrict__ reg_part,
                                                     float* __restrict__ out) {
    int t = threadIdx.x;
    float s1 = 0.f, s2 = 0.f;
    for (int i = t; i < 512;    i += 256) s1 += bpp_part[i];
    for (int i = t; i < NTILES; i += 256) s2 += reg_part[i];
    __shared__ float r1[256], r2[256];
    r1[t] = s1; r2[t] = s2;
    __syncthreads();
    #pragma unroll
    for (int s = 128; s; s >>= 1) {
        if (t < s) { r1[t] += r1[t + s]; r2[t] += r2[t + s]; }
        __syncthreads();
    }
    if (t == 0) { out[0] = r1[0]; out[1] = r2[0]; }
}

extern "C" void kernel_launch(void* const* d_in, const int* in_sizes, int n_in,
                              void* d_out, int out_size, void* d_ws, size_t ws_size,
                              hipStream_t stream) {
    const int*   user_id    = (const int*)  d_in[0];
    const int*   pos_id     = (const int*)  d_in[1];
    const int*   neg_id     = (const int*)  d_in[2];
    const float* user_table = (const float*)d_in[3];
    const float* item_table = (const float*)d_in[4];
    const float* D          = (const float*)d_in[5];
    float* out = (float*)d_out;

    float* ws          = (float*)d_ws;
    int*   sorted_id   = (int*)ws;                       // NTOT
    int*   sorted_orig = sorted_id + NTOT;               // NTOT
    float* e           = (float*)(sorted_orig + NTOT);   // NTOT*EMBED
    float* sq          = e  + NTOT * EMBED;              // NTOT
    float* bpp_part    = sq + NTOT;                      // 512
    float* reg_part    = bpp_part + 512;                 // NTILES

    bpp_kernel<<<BATCH / 4, 256, 0, stream>>>(user_id, pos_id, neg_id, user_table, item_table, bpp_part);
    sort_kernel<<<1, 1024, 0, stream>>>(pos_id, neg_id, sorted_id, sorted_orig);
    prep_kernel<<<NTOT / 4, 256, 0, stream>>>(sorted_id, item_table, e, sq);
    reg_kernel<<<NTILES, 256, 0, stream>>>(e, sq, sorted_id, sorted_orig, D, reg_part);
    reduce_kernel<<<1, 256, 0, stream>>>(bpp_part, reg_part, out);
}

// Round 3
// 52.736 us; speedup vs baseline: 2.7170x; 1.9784x over previous
//
#include <hip/hip_runtime.h>
#include <math.h>

#define EMBED   64
#define BATCH   2048
#define NTOT    4096
#define NITEMS  10000
#define TILE    64
#define NT      64               // NTOT/TILE
#define NTILES  2080             // NT*(NT+1)/2, == 8*260
#define SROW    72               // padded bf16 row stride (144 B)

#define NB_NORM 625              // 625*16 = 10000 rows
#define B_BPP0  (1 + NB_NORM)    // 626
#define NB_BPP  128              // 128*16 = 2048 batch elems
#define GRID1   (B_BPP0 + NB_BPP)

typedef __attribute__((ext_vector_type(8))) short short8;
typedef __attribute__((ext_vector_type(4))) float f32x4;

__device__ __forceinline__ unsigned short f2bf(float f) {   // RNE fp32->bf16
    unsigned u = __float_as_uint(f);
    return (unsigned short)((u + 0x7FFFu + ((u >> 16) & 1u)) >> 16);
}

// block 0: counting sort of (id, orig) keys; blocks 1..625: item norms;
// blocks 626..753: bpp softplus partials. All independent -> run concurrently.
__global__ __launch_bounds__(1024) void combo_kernel(
    const int* __restrict__ user_id, const int* __restrict__ pos_id,
    const int* __restrict__ neg_id, const float* __restrict__ user_table,
    const float* __restrict__ item_table,
    int* __restrict__ sorted_id, int* __restrict__ sorted_orig,
    float* __restrict__ norms, float* __restrict__ bpp_part)
{
    int blk = blockIdx.x, t = threadIdx.x;
    if (blk == 0) {
        __shared__ int hist[NITEMS];
        __shared__ unsigned key2[NTOT];
        __shared__ int scanbuf[1024];
        for (int i = t; i < NITEMS; i += 1024) hist[i] = 0;
        __syncthreads();
        for (int i = t; i < NTOT; i += 1024) {
            int id = (i < BATCH) ? pos_id[i] : neg_id[i - BATCH];
            atomicAdd(&hist[id], 1);
        }
        __syncthreads();
        // exclusive scan over 10000 bins: 10 bins/thread + Hillis-Steele
        int b0 = t * 10, bend = min(b0 + 10, NITEMS);
        int s = 0;
        for (int b = b0; b < bend; ++b) s += hist[b];
        scanbuf[t] = s;
        __syncthreads();
        for (int off = 1; off < 1024; off <<= 1) {
            int x = scanbuf[t];
            int y = (t >= off) ? scanbuf[t - off] : 0;
            __syncthreads();
            scanbuf[t] = x + y;
            __syncthreads();
        }
        int running = scanbuf[t] - s;
        for (int b = b0; b < bend; ++b) { int c = hist[b]; hist[b] = running; running += c; }
        __syncthreads();
        // scatter (atomic within bin), then canonicalize equal-id runs by orig
        for (int i = t; i < NTOT; i += 1024) {
            int id = (i < BATCH) ? pos_id[i] : neg_id[i - BATCH];
            int pos = atomicAdd(&hist[id], 1);
            key2[pos] = ((unsigned)id << 12) | (unsigned)i;
        }
        __syncthreads();
        for (int p = 0; p < 16; ++p) {          // odd-even passes; runs <=16 whp
            int start = p & 1;
            for (int q = t; q < NTOT / 2; q += 1024) {
                int a = 2 * q + start;
                if (a + 1 < NTOT) {
                    unsigned x = key2[a], y = key2[a + 1];
                    if (x > y) { key2[a] = y; key2[a + 1] = x; }
                }
            }
            __syncthreads();
        }
        for (int i = t; i < NTOT; i += 1024) {
            sorted_id[i]   = (int)(key2[i] >> 12);
            sorted_orig[i] = (int)(key2[i] & 4095u);
        }
    } else if (blk < B_BPP0) {
        int row  = (blk - 1) * 16 + (t >> 6);
        int lane = t & 63;
        float v = item_table[row * EMBED + lane];
        float sft = v * v;
        #pragma unroll
        for (int off = 32; off; off >>= 1) sft += __shfl_xor(sft, off, 64);
        if (lane == 0) norms[row] = sft;
    } else {
        int b    = (blk - B_BPP0) * 16 + (t >> 6);
        int lane = t & 63;
        float u = user_table[user_id[b] * EMBED + lane];
        float p = item_table[pos_id[b]  * EMBED + lane];
        float n = item_table[neg_id[b]  * EMBED + lane];
        float dp = u * p, dn = u * n;
        #pragma unroll
        for (int off = 32; off; off >>= 1) {
            dp += __shfl_xor(dp, off, 64);
            dn += __shfl_xor(dn, off, 64);
        }
        float x = dn - dp;
        float sp = fmaxf(x, 0.f) + log1pf(expf(-fabsf(x)));
        __shared__ float red[16];
        if (lane == 0) red[t >> 6] = sp;
        __syncthreads();
        if (t == 0) {
            float ssum = 0.f;
            for (int w = 0; w < 16; ++w) ssum += red[w];
            bpp_part[blk - B_BPP0] = ssum;
        }
    }
}

// One block per upper-tri 64x64 tile: MFMA dot tile + masked D-gather.
__global__ __launch_bounds__(256) void reg_kernel(
    const float* __restrict__ item_table,
    const int* __restrict__ sorted_id, const int* __restrict__ sorted_orig,
    const float* __restrict__ norms, const float* __restrict__ D,
    float* __restrict__ partials)
{
    __shared__ unsigned short sa[TILE][SROW];
    __shared__ unsigned short sb[TILE][SROW];
    __shared__ float sqi[TILE], sqj[TILE];
    __shared__ int idi[TILE], idj[TILE], idiN[TILE], idjN[TILE], ogi[TILE], ogj[TILE];
    __shared__ float red[256];

    // XCD-aware swizzle: 2080 = 8 * 260 exactly -> bijective
    int bs = blockIdx.x;
    int b  = (bs & 7) * (NTILES / 8) + (bs >> 3);
    int tI = 0, rem = b;
    while (rem >= NT - tI) { rem -= NT - tI; ++tI; }
    int tJ = tI + rem;

    int t = threadIdx.x;
    int r = t >> 2, c = t & 3;    // staging: row 0..63, 16-float chunk 0..3

    if (t < TILE) {
        int g = tI * TILE + t, id = sorted_id[g];
        sqi[t] = norms[id]; idi[t] = id; idiN[t] = id * NITEMS; ogi[t] = sorted_orig[g];
    } else if (t < 2 * TILE) {
        int rr = t - TILE, g = tJ * TILE + rr, id = sorted_id[g];
        sqj[rr] = norms[id]; idj[rr] = id; idjN[rr] = id * NITEMS; ogj[rr] = sorted_orig[g];
    }

    {   // stage both 64x64 fp32 slabs from item_table, convert to bf16
        int idI = sorted_id[tI * TILE + r];
        int idJ = sorted_id[tJ * TILE + r];
        const float4* srcI = (const float4*)&item_table[idI * EMBED + c * 16];
        const float4* srcJ = (const float4*)&item_table[idJ * EMBED + c * 16];
        float4 aI[4], aJ[4];
        #pragma unroll
        for (int k = 0; k < 4; ++k) { aI[k] = srcI[k]; aJ[k] = srcJ[k]; }
        short8 vI0, vI1, vJ0, vJ1;
        #pragma unroll
        for (int k = 0; k < 2; ++k) {
            vI0[4*k+0] = (short)f2bf(aI[k].x);  vI0[4*k+1] = (short)f2bf(aI[k].y);
            vI0[4*k+2] = (short)f2bf(aI[k].z);  vI0[4*k+3] = (short)f2bf(aI[k].w);
            vJ0[4*k+0] = (short)f2bf(aJ[k].x);  vJ0[4*k+1] = (short)f2bf(aJ[k].y);
            vJ0[4*k+2] = (short)f2bf(aJ[k].z);  vJ0[4*k+3] = (short)f2bf(aJ[k].w);
            vI1[4*k+0] = (short)f2bf(aI[k+2].x); vI1[4*k+1] = (short)f2bf(aI[k+2].y);
            vI1[4*k+2] = (short)f2bf(aI[k+2].z); vI1[4*k+3] = (short)f2bf(aI[k+2].w);
            vJ1[4*k+0] = (short)f2bf(aJ[k+2].x); vJ1[4*k+1] = (short)f2bf(aJ[k+2].y);
            vJ1[4*k+2] = (short)f2bf(aJ[k+2].z); vJ1[4*k+3] = (short)f2bf(aJ[k+2].w);
        }
        *(short8*)&sa[r][c * 16]     = vI0;
        *(short8*)&sa[r][c * 16 + 8] = vI1;
        *(short8*)&sb[r][c * 16]     = vJ0;
        *(short8*)&sb[r][c * 16 + 8] = vJ1;
    }
    __syncthreads();

    // MFMA: wave w owns rows [w*16, w*16+16) x all 64 cols; K=64 in 2 steps.
    int w = t >> 6, l = t & 63;
    int arow = w * 16 + (l & 15);
    int kb   = (l >> 4) * 8;            // per-lane k-element base
    f32x4 acc[4];
    #pragma unroll
    for (int cb = 0; cb < 4; ++cb) acc[cb] = (f32x4){0.f, 0.f, 0.f, 0.f};
    #pragma unroll
    for (int s = 0; s < 2; ++s) {
        short8 af = *(const short8*)&sa[arow][s * 32 + kb];
        #pragma unroll
        for (int cb = 0; cb < 4; ++cb) {
            short8 bf = *(const short8*)&sb[cb * 16 + (l & 15)][s * 32 + kb];
            acc[cb] = __builtin_amdgcn_mfma_f32_16x16x32_bf16(af, bf, acc[cb], 0, 0, 0);
        }
    }

    // epilogue: C/D map col=lane&15, row=(lane>>4)*4+reg (m89-verified)
    float accsum = 0.f;
    #pragma unroll
    for (int cb = 0; cb < 4; ++cb) {
        #pragma unroll
        for (int rr = 0; rr < 4; ++rr) {
            int i_loc = w * 16 + (l >> 4) * 4 + rr;
            int j_loc = cb * 16 + (l & 15);
            int gi = tI * TILE + i_loc, gj = tJ * TILE + j_loc;
            float d2 = sqi[i_loc] + sqj[j_loc] - 2.f * acc[cb][rr];
            if (gi < gj && d2 > 0.f) {
                bool fwd = ogi[i_loc] < ogj[j_loc];
                int addr = fwd ? (idiN[i_loc] + idj[j_loc]) : (idjN[j_loc] + idi[i_loc]);
                accsum += D[addr] * sqrtf(d2);
            }
        }
    }

    red[t] = accsum;
    __syncthreads();
    #pragma unroll
    for (int s = 128; s; s >>= 1) {
        if (t < s) red[t] += red[t + s];
        __syncthreads();
    }
    if (t == 0) partials[b] = red[0];
}

__global__ __launch_bounds__(256) void reduce_kernel(const float* __restrict__ bpp_part,
                                                     const float* __restrict__ reg_part,
                                                     float* __restrict__ out) {
    int t = threadIdx.x;
    float s1 = 0.f, s2 = 0.f;
    for (int i = t; i < NB_BPP; i += 256) s1 += bpp_part[i];
    for (int i = t; i < NTILES; i += 256) s2 += reg_part[i];
    __shared__ float r1[256], r2[256];
    r1[t] = s1; r2[t] = s2;
    __syncthreads();
    #pragma unroll
    for (int s = 128; s; s >>= 1) {
        if (t < s) { r1[t] += r1[t + s]; r2[t] += r2[t + s]; }
        __syncthreads();
    }
    if (t == 0) { out[0] = r1[0]; out[1] = r2[0]; }
}

extern "C" void kernel_launch(void* const* d_in, const int* in_sizes, int n_in,
                              void* d_out, int out_size, void* d_ws, size_t ws_size,
                              hipStream_t stream) {
    const int*   user_id    = (const int*)  d_in[0];
    const int*   pos_id     = (const int*)  d_in[1];
    const int*   neg_id     = (const int*)  d_in[2];
    const float* user_table = (const float*)d_in[3];
    const float* item_table = (const float*)d_in[4];
    const float* D          = (const float*)d_in[5];
    float* out = (float*)d_out;

    int*   sorted_id   = (int*)d_ws;                    // 4096
    int*   sorted_orig = sorted_id + NTOT;              // 4096
    float* norms       = (float*)(sorted_orig + NTOT);  // 10000
    float* bpp_part    = norms + NITEMS;                // 128
    float* reg_part    = bpp_part + NB_BPP;             // 2080

    combo_kernel<<<GRID1, 1024, 0, stream>>>(user_id, pos_id, neg_id, user_table,
                                             item_table, sorted_id, sorted_orig,
                                             norms, bpp_part);
    reg_kernel<<<NTILES, 256, 0, stream>>>(item_table, sorted_id, sorted_orig,
                                           norms, D, reg_part);
    reduce_kernel<<<1, 256, 0, stream>>>(bpp_part, reg_part, out);
}